// Round 16
// baseline (194.286 us; speedup 1.0000x reference)
//
#include <hip/hip_runtime.h>
#include <hip/hip_bf16.h>

// Problem constants
#define BB   2
#define TT   2048
#define DD   1024
#define HH   16
#define EE   64
#define BT   4096   // BB*TT

typedef __attribute__((ext_vector_type(8))) short bf16x8;    // 8 bf16 = 4 VGPRs
typedef __attribute__((ext_vector_type(4))) float floatx4;   // 16x16 mfma C/D
typedef __attribute__((ext_vector_type(16))) float floatx16; // 32x32 mfma C/D

__device__ __forceinline__ unsigned short f2bf(float f) {
  unsigned int x = __float_as_uint(f);
  x += 0x7fffu + ((x >> 16) & 1u);   // round-to-nearest-even
  return (unsigned short)(x >> 16);
}
__device__ __forceinline__ unsigned int pack2u(float a, float b) {
  union { __hip_bfloat162 h; unsigned int u; } r;
  r.h = __float22bfloat162_rn(make_float2(a, b));
  return r.u;
}
// 8x fp32 -> 8x bf16 (RNE) packed; uses v_cvt_pk_bf16_f32 on gfx950
__device__ __forceinline__ uint4 pack8(const float4& a, const float4& b) {
  union { uint4 u; __hip_bfloat162 h[4]; } r;
  r.h[0] = __float22bfloat162_rn(make_float2(a.x, a.y));
  r.h[1] = __float22bfloat162_rn(make_float2(a.z, a.w));
  r.h[2] = __float22bfloat162_rn(make_float2(b.x, b.y));
  r.h[3] = __float22bfloat162_rn(make_float2(b.z, b.w));
  return r.u;
}
// async global->LDS, 16 B per lane; LDS dest = wave-uniform base + lane*16
__device__ __forceinline__ void ld16(unsigned short* lds, const unsigned short* g) {
  __builtin_amdgcn_global_load_lds(
      (const __attribute__((address_space(1))) unsigned int*)g,
      (__attribute__((address_space(3))) unsigned int*)lds, 16, 0, 0);
}

// ---------------------------------------------------------------------------
// Pre-pass: fp32 -> bf16 for X, [Wq;Wkv], Wout. One group = 8 elems.
// ---------------------------------------------------------------------------
#define GX   524288
#define GWQ  131072
#define GWKV 262144
#define GWO  131072

__global__ __launch_bounds__(256) void convert_kernel(
    const float* __restrict__ X,  const float* __restrict__ Wq,
    const float* __restrict__ Wkv, const float* __restrict__ Wout,
    unsigned short* __restrict__ Xb, unsigned short* __restrict__ Wb,
    unsigned short* __restrict__ Wob) {
  int g = blockIdx.x * 256 + threadIdx.x;
  const float* src; unsigned short* dst; int gi;
  if (g < GX)                        { src = X;    dst = Xb;  gi = g; }
  else if ((g -= GX) < GWQ)          { src = Wq;   dst = Wb;  gi = g; }
  else if ((g -= GWQ) < GWKV)        { src = Wkv;  dst = Wb + (size_t)GWQ * 8; gi = g; }
  else                               { src = Wout; dst = Wob; gi = g - GWKV; }
  const float4* s4 = reinterpret_cast<const float4*>(src) + (size_t)gi * 2;
  float4 a = s4[0], b = s4[1];
  reinterpret_cast<uint4*>(dst)[gi] = pack8(a, b);
}

// ---------------------------------------------------------------------------
// MFMA GEMM 1 (m97-style, frozen): C = Xb[4096,1024] @ Wb[3072,1024]^T.
// NOTE (R12 lesson): natural dispatch d=y*24+x already pins bn-panel%8 ->
// XCD (24 % 8 == 0); explicit remap refuted (perturbs producer->consumer
// L2 placement). Q/K/V epilogues LDS-staged, coalesced 16B stores.
// ---------------------------------------------------------------------------
__global__ __launch_bounds__(256) void gemm_qkv_mfma(
    const unsigned short* __restrict__ Xb,
    const unsigned short* __restrict__ Wb,
    unsigned short* __restrict__ Qh,
    unsigned short* __restrict__ Kh,
    unsigned short* __restrict__ Vt) {
  // GEMM phase: As = smem[0:8192], Bs = smem[8192:16384]
  // Epilogues: reused as 128x136 staging buffer (17408 ushorts = 34 KB)
  __shared__ __align__(16) unsigned short smem[128 * 136];
  unsigned short* As = smem;
  unsigned short* Bs = smem + 128 * 64;
  const int tid  = threadIdx.x;
  const int lane = tid & 63, w = tid >> 6;
  const int wm = w >> 1, wn = w & 1;
  const int q = lane >> 4, c = lane & 15;
  const int bm0 = blockIdx.y * 128;
  const int bn0 = blockIdx.x * 128;
  const unsigned short* Ag = Xb + (size_t)bm0 * DD;
  const unsigned short* Bg = Wb + (size_t)bn0 * DD;

  floatx4 acc[4][4];
#pragma unroll
  for (int i = 0; i < 4; ++i)
#pragma unroll
    for (int j = 0; j < 4; ++j) acc[i][j] = (floatx4){0.f, 0.f, 0.f, 0.f};

  int prow[4], pch[4];
#pragma unroll
  for (int t = 0; t < 4; ++t) {
    int s = (w * 4 + t) * 64 + lane;
    prow[t] = s >> 3;
    pch[t]  = (s & 7) ^ (prow[t] & 7);
  }
  int aoff[4][2], boff[4][2];
#pragma unroll
  for (int i = 0; i < 4; ++i)
#pragma unroll
    for (int h = 0; h < 2; ++h) {
      aoff[i][h] = (wm * 64 + i * 16 + c) * 64 + (((q + h * 4) ^ (c & 7)) << 3);
      boff[i][h] = (wn * 64 + i * 16 + c) * 64 + (((q + h * 4) ^ (c & 7)) << 3);
    }

  for (int kk = 0; kk < DD; kk += 64) {
    __syncthreads();
#pragma unroll
    for (int t = 0; t < 4; ++t) {
      int i = w * 4 + t;
      ld16(&As[i * 512], &Ag[(size_t)prow[t] * DD + kk + pch[t] * 8]);
      ld16(&Bs[i * 512], &Bg[(size_t)prow[t] * DD + kk + pch[t] * 8]);
    }
    __syncthreads();
    bf16x8 af[4][2], bfr[4][2];
#pragma unroll
    for (int i = 0; i < 4; ++i)
#pragma unroll
      for (int h = 0; h < 2; ++h) {
        af[i][h]  = *reinterpret_cast<const bf16x8*>(&As[aoff[i][h]]);
        bfr[i][h] = *reinterpret_cast<const bf16x8*>(&Bs[boff[i][h]]);
      }
#pragma unroll
    for (int i = 0; i < 4; ++i)
#pragma unroll
      for (int j = 0; j < 4; ++j) {
        acc[i][j] = __builtin_amdgcn_mfma_f32_16x16x32_bf16(af[i][0], bfr[j][0], acc[i][j], 0, 0, 0);
        acc[i][j] = __builtin_amdgcn_mfma_f32_16x16x32_bf16(af[i][1], bfr[j][1], acc[i][j], 0, 0, 0);
      }
  }

  const int region = bn0 >> 10;   // 0=Q, 1=K, 2=V
  if (region < 2) {
    // ---- Q/K: stage [m][n] in LDS, then coalesced 16B stores along e ----
    // Q scale: e^-0.5 * log2(e) so attention can use raw exp2
    const float scl = (region == 0) ? 0.18033688011112042f : 1.0f;
    __syncthreads();   // all waves done with As/Bs reads before reuse
    unsigned short* tb = smem;   // [128 m][136 stride], col = n
#pragma unroll
    for (int i = 0; i < 4; ++i) {
#pragma unroll
      for (int j = 0; j < 4; ++j) {
        int n  = wn * 64 + j * 16 + c;
        int m0 = wm * 64 + i * 16 + q * 4;
#pragma unroll
        for (int reg = 0; reg < 4; ++reg)
          tb[(m0 + reg) * 136 + n] = f2bf(acc[i][j][reg] * scl);
      }
    }
    __syncthreads();
    unsigned short* dst = (region == 0) ? Qh : Kh;
    const int b   = bm0 >> 11;
    const int t0  = bm0 & 2047;
    const int nb0 = bn0 & 1023;
    const int oct = tid & 15;
    const int nb  = nb0 + oct * 8;
    const int h   = nb >> 6, e = nb & 63;
#pragma unroll
    for (int it = 0; it < 8; ++it) {
      int tr = it * 16 + (tid >> 4);
      uint4 vv = *reinterpret_cast<const uint4*>(&tb[tr * 136 + oct * 8]);
      *reinterpret_cast<uint4*>(
          &dst[((size_t)((b * HH + h) * TT + t0 + tr)) * EE + e]) = vv;
    }
  } else {
    // ---- V: transpose through LDS, then coalesced 16 B stores along t ----
    __syncthreads();   // all waves done with As/Bs reads before reuse
    unsigned short* tb = smem;   // [128 n][136 stride], col = m (t)
#pragma unroll
    for (int i = 0; i < 4; ++i) {
#pragma unroll
      for (int j = 0; j < 4; ++j) {
        int nl = wn * 64 + j * 16 + c;
        int ml = wm * 64 + i * 16 + q * 4;
        ushort4 pk;
        pk.x = f2bf(acc[i][j][0]);
        pk.y = f2bf(acc[i][j][1]);
        pk.z = f2bf(acc[i][j][2]);
        pk.w = f2bf(acc[i][j][3]);
        *reinterpret_cast<ushort4*>(&tb[nl * 136 + ml]) = pk;  // 8 B aligned
      }
    }
    __syncthreads();
    const int b  = bm0 >> 11;
    const int t0 = bm0 & 2047;
    const int nb0 = bn0 & 1023;
    const int lr = tid & 15;
#pragma unroll
    for (int it = 0; it < 8; ++it) {
      int nl = it * 16 + (tid >> 4);
      int nb = nb0 + nl;
      int h = nb >> 6, e = nb & 63;
      uint4 vv = *reinterpret_cast<const uint4*>(&tb[nl * 136 + lr * 8]);
      *reinterpret_cast<uint4*>(
          &Vt[((size_t)(b * HH + h) * EE + e) * TT + t0 + lr * 8]) = vv;
    }
  }
}

// ---------------------------------------------------------------------------
// MFMA flash attention v12 (best-known, frozen): no setprio (R15: removing
// it was -13% — m190 case: barrier-synced 2-wave blocks, prioritized MFMA
// starves partner wave's staging). Padded conflict-free V (reg-staged, T14
// async split), K gload_lds + XOR, MFMA row-sum softmax, exp2 softmax.
// 32x32 layouts: A/B: m|n=lane&31, k=(lane>>5)*8+j;
//                C/D: col=lane&31, row=(reg&3)+8*(reg>>2)+4*(lane>>5).
// XCD pinning: xcd=flat&7 (4 bh x 512 KB = 2 MB < 4 MB L2 per XCD).
// ---------------------------------------------------------------------------
#define NKT 32   // 2048 / 64 k-tiles
#define VST 68   // padded V row stride (ushorts): 136B = 2-bank shift/row

#define ATILE(P, PREF, VMC)                                                    \
  do {                                                                         \
    if (PREF) {                                                                \
      _Pragma("unroll")                                                        \
      for (int t = 0; t < 4; ++t) {                                            \
        vreg[t] = *reinterpret_cast<const uint4*>(vpre[t]);                    \
        vpre[t] += 64;                                                         \
      }                                                                        \
      _Pragma("unroll")                                                        \
      for (int t = 0; t < 4; ++t) {                                            \
        ld16(&Kbuf[((P) ^ 1) * 4096 + (t * 2 + w) * 512], kpre[t]);            \
        kpre[t] += 4096;                                                       \
      }                                                                        \
    }                                                                          \
    asm volatile("s_waitcnt vmcnt(" VMC ")" ::: "memory");                     \
    asm volatile("s_barrier" ::: "memory");                                    \
    bf16x8 kf[2][4];                                                           \
    _Pragma("unroll")                                                          \
    for (int nt = 0; nt < 2; ++nt)                                             \
      _Pragma("unroll")                                                        \
      for (int kc = 0; kc < 4; ++kc)                                           \
        kf[nt][kc] = *reinterpret_cast<const bf16x8*>(                         \
            &Kbuf[(P) * 4096 + koff[nt][kc]]);                                 \
    floatx16 sacc[2];                                                          \
    _Pragma("unroll")                                                          \
    for (int nt = 0; nt < 2; ++nt) {                                           \
      sacc[nt] = __builtin_amdgcn_mfma_f32_32x32x16_bf16(kf[nt][0], qf[0], zf, 0, 0, 0); \
      _Pragma("unroll")                                                        \
      for (int kc = 1; kc < 4; ++kc)                                           \
        sacc[nt] = __builtin_amdgcn_mfma_f32_32x32x16_bf16(kf[nt][kc], qf[kc], sacc[nt], 0, 0, 0); \
    }                                                                          \
    unsigned int pp[2][8];                                                     \
    _Pragma("unroll")                                                          \
    for (int nt = 0; nt < 2; ++nt)                                             \
      _Pragma("unroll")                                                        \
      for (int r = 0; r < 8; ++r) {                                            \
        float e0 = __builtin_amdgcn_exp2f(sacc[nt][2 * r]);                    \
        float e1 = __builtin_amdgcn_exp2f(sacc[nt][2 * r + 1]);                \
        pp[nt][r] = pack2u(e0, e1);                                            \
      }                                                                        \
    _Pragma("unroll")                                                          \
    for (int nt = 0; nt < 2; ++nt)                                             \
      _Pragma("unroll")                                                        \
      for (int kcp = 0; kcp < 2; ++kcp) {                                      \
        union { unsigned int u[4]; bf16x8 v; } pf;                             \
        pf.u[0] = pp[nt][4 * kcp + 0]; pf.u[1] = pp[nt][4 * kcp + 1];          \
        pf.u[2] = pp[nt][4 * kcp + 2]; pf.u[3] = pp[nt][4 * kcp + 3];          \
        lacc = __builtin_amdgcn_mfma_f32_32x32x16_bf16(pf.v, onesf.v, lacc, 0, 0, 0); \
        _Pragma("unroll")                                                      \
        for (int eh = 0; eh < 2; ++eh) {                                       \
          const int cc = nt * 4 + 2 * kcp;                                     \
          uint2 v0 = *reinterpret_cast<const uint2*>(                          \
              &Vbuf[(P) * 4352 + voff[eh][cc]]);                               \
          uint2 v1 = *reinterpret_cast<const uint2*>(                          \
              &Vbuf[(P) * 4352 + voff[eh][cc + 1]]);                           \
          union { unsigned int u[4]; bf16x8 v; } vf;                           \
          vf.u[0] = v0.x; vf.u[1] = v0.y; vf.u[2] = v1.x; vf.u[3] = v1.y;      \
          o_acc[eh] = __builtin_amdgcn_mfma_f32_32x32x16_bf16(pf.v, vf.v, o_acc[eh], 0, 0, 0); \
        }                                                                      \
      }                                                                        \
    if (PREF) {                                                                \
      asm volatile("s_waitcnt vmcnt(4)" ::: "memory");                         \
      _Pragma("unroll")                                                        \
      for (int t = 0; t < 4; ++t) {                                            \
        unsigned short* vd = &Vbuf[((P) ^ 1) * 4352 + vwoff[t]];               \
        *reinterpret_cast<uint2*>(vd)     = make_uint2(vreg[t].x, vreg[t].y);  \
        *reinterpret_cast<uint2*>(vd + 4) = make_uint2(vreg[t].z, vreg[t].w);  \
      }                                                                        \
      asm volatile("s_waitcnt lgkmcnt(0)" ::: "memory");                       \
    }                                                                          \
    asm volatile("s_barrier" ::: "memory");                                    \
  } while (0)

__global__ __launch_bounds__(128) void attn_kernel(
    const unsigned short* __restrict__ Qh,
    const unsigned short* __restrict__ Kh,
    const unsigned short* __restrict__ Vtg,
    unsigned short* __restrict__ Aw) {
  // Kbuf: [2][4096] at smem[0]; Vbuf: [2][64][VST=68] at smem[8192]
  __shared__ __align__(16) unsigned short smem[16896];   // 33 KB

  const int tid  = threadIdx.x;   // 0..127
  const int lane = tid & 63;
  const int w    = tid >> 6;      // 0..1: q-row half
  const int n31  = lane & 31;
  const int g    = lane >> 5;

  // XCD-aware remap (bijective over flat 0..1023): xcd = flat&7
  const int flat = blockIdx.y * 32 + blockIdx.x;
  const int idx  = flat >> 3;                    // 0..127
  const int bh   = (flat & 7) * 4 + (idx >> 5);  // 0..31
  const int qt   = idx & 31;                     // 0..31
  const size_t base = (size_t)bh * TT * EE;
  const unsigned short* Qp = Qh + base + (size_t)(qt * 64 + w * 32) * EE;
  const unsigned short* Kp = Kh + base;
  const unsigned short* Vp = Vtg + base;

  unsigned short* Kbuf = smem;          // [2][4096]
  unsigned short* Vbuf = smem + 8192;   // [2][64*VST = 4352]

  // all-ones bf16 B-fragment for the row-sum MFMA (bf16 1.0 = 0x3F80)
  union { unsigned int u[4]; bf16x8 v; } onesf;
  onesf.u[0] = 0x3F803F80u; onesf.u[1] = 0x3F803F80u;
  onesf.u[2] = 0x3F803F80u; onesf.u[3] = 0x3F803F80u;

  // persistent zero C-operand for the first QK^T MFMA of each chain
  const floatx16 zf = (floatx16)(0.0f);

  // Q B-frags in registers: row n31 (of this wave's 32), e-chunk kc*16+g*8
  bf16x8 qf[4];
#pragma unroll
  for (int kc = 0; kc < 4; ++kc)
    qf[kc] = *reinterpret_cast<const bf16x8*>(
        &Qp[(size_t)n31 * EE + kc * 16 + g * 8]);

  // staging slots: block = 128 threads; 8 KB tile = 512 slots -> 4/thread
  int srow[4], sch[4], voct[4], vwoff[4];
#pragma unroll
  for (int t = 0; t < 4; ++t) {
    int s = (t * 2 + w) * 64 + lane;
    srow[t] = s >> 3;
    sch[t]  = (s & 7) ^ (srow[t] & 7);   // K XOR swizzle (unchanged)
    voct[t] = s & 7;                     // V: linear octet, no swizzle
    vwoff[t] = srow[t] * VST + voct[t] * 8;
  }

  // ---- loop-invariant LDS read offsets (ushort units within one buffer) ----
  int koff[2][4];
#pragma unroll
  for (int nt = 0; nt < 2; ++nt) {
    const int krow = nt * 32 + n31;
#pragma unroll
    for (int kc = 0; kc < 4; ++kc)
      koff[nt][kc] = krow * 64 + (((kc * 2 + g) ^ (krow & 7)) << 3);
  }
  int voff[2][8];
#pragma unroll
  for (int eh = 0; eh < 2; ++eh) {
    const int vrow = eh * 32 + n31;
#pragma unroll
    for (int cc = 0; cc < 8; ++cc)
      voff[eh][cc] = vrow * VST + cc * 8 + g * 4;   // 2-bank/row shift: free
  }

  // ---- strength-reduced prefetch pointers (start at tile 1) ----
  const unsigned short* kpre[4];
  const unsigned short* vpre[4];
#pragma unroll
  for (int t = 0; t < 4; ++t) {
    kpre[t] = Kp + (size_t)(64 + srow[t]) * EE + sch[t] * 8;
    vpre[t] = Vp + (size_t)srow[t] * TT + 64 + voct[t] * 8;
  }

  floatx16 o_acc[2];              // [eh]
  o_acc[0] = (floatx16)(0.0f);
  o_acc[1] = (floatx16)(0.0f);
  floatx16 lacc = (floatx16)(0.0f);   // row-sums of P (all 32 cols equal)

  uint4 vreg[4];                  // in-flight V tile (reg-staged)

  // ---- prologue: tile 0. V(0) loads first (oldest), K(0) DMAs second ----
#pragma unroll
  for (int t = 0; t < 4; ++t)
    vreg[t] = *reinterpret_cast<const uint4*>(
        Vp + (size_t)srow[t] * TT + voct[t] * 8);
#pragma unroll
  for (int t = 0; t < 4; ++t)
    ld16(&Kbuf[(t * 2 + w) * 512], Kp + (size_t)srow[t] * EE + sch[t] * 8);
  asm volatile("s_waitcnt vmcnt(4)" ::: "memory");   // retire V(0) regs
#pragma unroll
  for (int t = 0; t < 4; ++t) {
    unsigned short* vd = &Vbuf[vwoff[t]];
    *reinterpret_cast<uint2*>(vd)     = make_uint2(vreg[t].x, vreg[t].y);
    *reinterpret_cast<uint2*>(vd + 4) = make_uint2(vreg[t].z, vreg[t].w);
  }
  asm volatile("s_waitcnt lgkmcnt(0)" ::: "memory");
  // K(0) x4 still in flight; tile 0's vmcnt(8) retires them.

  // tiles 0..29 (buffer parity literal per half), then peel 30 and 31
  for (int kt2 = 0; kt2 < 15; ++kt2) {
    ATILE(0, true, "8");
    ATILE(1, true, "8");
  }
  ATILE(0, true, "8");    // tile 30: prefetch 31 (K->Kbuf[1], V->Vbuf[1])
  ATILE(1, false, "0");   // tile 31: drain K(31), no prefetch

  // ---- epilogue: lacc[reg] already holds this lane's row total ----
  const int b = bh >> 4, h = bh & 15;
#pragma unroll
  for (int eh = 0; eh < 2; ++eh)
#pragma unroll
    for (int reg = 0; reg < 16; ++reg) {
      int qrl = (reg & 3) + 8 * (reg >> 2) + 4 * g;
      int t = qt * 64 + w * 32 + qrl;
      Aw[((size_t)(b * TT + t)) * DD + h * EE + eh * 32 + n31] =
          f2bf(o_acc[eh][reg] * (1.0f / lacc[reg]));
    }
}

// ---------------------------------------------------------------------------
// MFMA GEMM 2 v13: R8 tile (128x64x64, grid 512 = 2 blocks/CU) + attn-style
// counted-vmcnt double-buffer. gemm_out runs at only 2 blocks/CU (grid-
// capped) where the m99-null (TLP hides the __syncthreads full-drain at
// 3 blocks/CU) does NOT apply. Dbuf LDS 48 KB -> still 2 blocks/CU, zero
// occupancy cost. Ledger: 6 DMAs/wave/tile (4 A + 2 B); steady tile enters
// with own 6 in flight, issues next-tile 6, vmcnt(6) retires own; last tile
// peeled with vmcnt(0). Raw s_barrier pair per tile (cross-wave LDS vis).
// ---------------------------------------------------------------------------
#define GTILE(P, PREF, VMC)                                                    \
  do {                                                                         \
    if (PREF) {                                                                \
      _Pragma("unroll")                                                        \
      for (int t = 0; t < 4; ++t) {                                            \
        ld16(&As[((P) ^ 1) * 8192 + (w * 4 + t) * 512], apre[t]);              \
        apre[t] += 64;                                                         \
      }                                                                        \
      _Pragma("unroll")                                                        \
      for (int t = 0; t < 2; ++t) {                                            \
        ld16(&Bs[((P) ^ 1) * 4096 + (w * 2 + t) * 512], bpre[t]);              \
        bpre[t] += 64;                                                         \
      }                                                                        \
    }                                                                          \
    asm volatile("s_waitcnt vmcnt(" VMC ")" ::: "memory");                     \
    asm volatile("s_barrier" ::: "memory");                                    \
    bf16x8 af[4][2], bfr[2][2];                                                \
    _Pragma("unroll")                                                          \
    for (int h = 0; h < 2; ++h) {                                              \
      const int ksw = ((q + h * 4) ^ (c & 7)) << 3;                            \
      _Pragma("unroll")                                                        \
      for (int i = 0; i < 4; ++i)                                              \
        af[i][h] = *reinterpret_cast<const bf16x8*>(                           \
            &As[(P) * 8192 + (wm * 64 + i * 16 + c) * 64 + ksw]);              \
      _Pragma("unroll")                                                        \
      for (int j = 0; j < 2; ++j)                                              \
        bfr[j][h] = *reinterpret_cast<const bf16x8*>(                          \
            &Bs[(P) * 4096 + (wn * 32 + j * 16 + c) * 64 + ksw]);              \
    }                                                                          \
    _Pragma("unroll")                                                          \
    for (int i = 0; i < 4; ++i)                                                \
      _Pragma("unroll")                                                        \
      for (int j = 0; j < 2; ++j) {                                            \
        acc[i][j] = __builtin_amdgcn_mfma_f32_16x16x32_bf16(af[i][0], bfr[j][0], acc[i][j], 0, 0, 0); \
        acc[i][j] = __builtin_amdgcn_mfma_f32_16x16x32_bf16(af[i][1], bfr[j][1], acc[i][j], 0, 0, 0); \
      }                                                                        \
    asm volatile("s_barrier" ::: "memory");                                    \
  } while (0)

__global__ __launch_bounds__(256) void gemm_out_mfma(
    const unsigned short* __restrict__ A,
    const unsigned short* __restrict__ Wob,
    const float* __restrict__ bias,
    float* __restrict__ out) {
  __shared__ __align__(16) unsigned short As[2 * 128 * 64];  // 32 KB dbuf
  __shared__ __align__(16) unsigned short Bs[2 * 64 * 64];   // 16 KB dbuf
  const int tid  = threadIdx.x;
  const int lane = tid & 63, w = tid >> 6;
  const int wm = w >> 1, wn = w & 1;
  const int q = lane >> 4, c = lane & 15;
  const int bm0 = blockIdx.y * 128;
  const int bn0 = blockIdx.x * 64;
  const unsigned short* Ag = A + (size_t)bm0 * DD;
  const unsigned short* Bg = Wob + (size_t)bn0 * DD;

  floatx4 acc[4][2];
#pragma unroll
  for (int i = 0; i < 4; ++i)
#pragma unroll
    for (int j = 0; j < 2; ++j) acc[i][j] = (floatx4){0.f, 0.f, 0.f, 0.f};

  int parow[4], pach[4];
#pragma unroll
  for (int t = 0; t < 4; ++t) {
    int s = (w * 4 + t) * 64 + lane;
    parow[t] = s >> 3;
    pach[t]  = (s & 7) ^ (parow[t] & 7);
  }
  int pbrow[2], pbch[2];
#pragma unroll
  for (int t = 0; t < 2; ++t) {
    int s = (w * 2 + t) * 64 + lane;
    pbrow[t] = s >> 3;
    pbch[t]  = (s & 7) ^ (pbrow[t] & 7);
  }

  // strength-reduced prefetch pointers (start at K-step 1)
  const unsigned short* apre[4];
  const unsigned short* bpre[2];
#pragma unroll
  for (int t = 0; t < 4; ++t)
    apre[t] = Ag + (size_t)parow[t] * DD + 64 + pach[t] * 8;
#pragma unroll
  for (int t = 0; t < 2; ++t)
    bpre[t] = Bg + (size_t)pbrow[t] * DD + 64 + pbch[t] * 8;

  // prologue: K-step 0 into buf 0
#pragma unroll
  for (int t = 0; t < 4; ++t)
    ld16(&As[(w * 4 + t) * 512], Ag + (size_t)parow[t] * DD + pach[t] * 8);
#pragma unroll
  for (int t = 0; t < 2; ++t)
    ld16(&Bs[(w * 2 + t) * 512], Bg + (size_t)pbrow[t] * DD + pbch[t] * 8);

  // K-steps 0..13 (7 literal-parity pairs), then peel 14 and 15
  for (int kt2 = 0; kt2 < 7; ++kt2) {
    GTILE(0, true, "6");
    GTILE(1, true, "6");
  }
  GTILE(0, true, "6");    // step 14: prefetch 15 -> buf1
  GTILE(1, false, "0");   // step 15: drain, no prefetch

#pragma unroll
  for (int i = 0; i < 4; ++i) {
#pragma unroll
    for (int j = 0; j < 2; ++j) {
      int n = bn0 + wn * 32 + j * 16 + c;
      float bv = bias[n];
#pragma unroll
      for (int reg = 0; reg < 4; ++reg) {
        int m = bm0 + wm * 64 + i * 16 + q * 4 + reg;
        out[(size_t)m * DD + n] = acc[i][j][reg] + bv;
      }
    }
  }
}

// ---------------------------------------------------------------------------
extern "C" void kernel_launch(void* const* d_in, const int* in_sizes, int n_in,
                              void* d_out, int out_size, void* d_ws, size_t ws_size,
                              hipStream_t stream) {
  const float* X    = (const float*)d_in[0];
  const float* Wq   = (const float*)d_in[1];
  const float* Wkv  = (const float*)d_in[2];
  const float* Wout = (const float*)d_in[3];
  const float* bout = (const float*)d_in[4];
  float* out = (float*)d_out;

  unsigned short* Qh  = (unsigned short*)d_ws;            // [32][2048][64]
  unsigned short* Kh  = Qh + (size_t)BT * DD;             // [32][2048][64]
  unsigned short* Vt  = Kh + (size_t)BT * DD;             // [32][64][2048]
  unsigned short* Aw  = Vt + (size_t)BT * DD;             // [4096][1024]
  unsigned short* Xb  = Aw;                               // OVERLAY: dead before attn writes Aw
  unsigned short* Wb  = Aw + (size_t)BT * DD;             // [3072][1024]
  unsigned short* Wob = Wb + (size_t)3 * 1024 * DD;       // [1024][1024]

  convert_kernel<<<dim3(4096), 256, 0, stream>>>(X, Wq, Wkv, Wout, Xb, Wb, Wob);
  gemm_qkv_mfma<<<dim3(24, 32), 256, 0, stream>>>(Xb, Wb, Qh, Kh, Vt);
  attn_kernel<<<dim3(32, 32), 128, 0, stream>>>(Qh, Kh, Vt, Aw);
  gemm_out_mfma<<<dim3(16, 32), 256, 0, stream>>>(Aw, Wob, bout, out);
}

// Round 18
// 189.430 us; speedup vs baseline: 1.0256x; 1.0256x over previous
//
#include <hip/hip_runtime.h>
#include <hip/hip_bf16.h>

// Problem constants
#define BB   2
#define TT   2048
#define DD   1024
#define HH   16
#define EE   64
#define BT   4096   // BB*TT

typedef __attribute__((ext_vector_type(8))) short bf16x8;    // 8 bf16 = 4 VGPRs
typedef __attribute__((ext_vector_type(4))) float floatx4;   // 16x16 mfma C/D
typedef __attribute__((ext_vector_type(16))) float floatx16; // 32x32 mfma C/D

__device__ __forceinline__ unsigned short f2bf(float f) {
  unsigned int x = __float_as_uint(f);
  x += 0x7fffu + ((x >> 16) & 1u);   // round-to-nearest-even
  return (unsigned short)(x >> 16);
}
__device__ __forceinline__ unsigned int pack2u(float a, float b) {
  union { __hip_bfloat162 h; unsigned int u; } r;
  r.h = __float22bfloat162_rn(make_float2(a, b));
  return r.u;
}
// 8x fp32 -> 8x bf16 (RNE) packed; uses v_cvt_pk_bf16_f32 on gfx950
__device__ __forceinline__ uint4 pack8(const float4& a, const float4& b) {
  union { uint4 u; __hip_bfloat162 h[4]; } r;
  r.h[0] = __float22bfloat162_rn(make_float2(a.x, a.y));
  r.h[1] = __float22bfloat162_rn(make_float2(a.z, a.w));
  r.h[2] = __float22bfloat162_rn(make_float2(b.x, b.y));
  r.h[3] = __float22bfloat162_rn(make_float2(b.z, b.w));
  return r.u;
}
// async global->LDS, 16 B per lane; LDS dest = wave-uniform base + lane*16
__device__ __forceinline__ void ld16(unsigned short* lds, const unsigned short* g) {
  __builtin_amdgcn_global_load_lds(
      (const __attribute__((address_space(1))) unsigned int*)g,
      (__attribute__((address_space(3))) unsigned int*)lds, 16, 0, 0);
}

// ---------------------------------------------------------------------------
// Pre-pass: fp32 -> bf16 for X, [Wq;Wkv], Wout. One group = 8 elems.
// ---------------------------------------------------------------------------
#define GX   524288
#define GWQ  131072
#define GWKV 262144
#define GWO  131072

__global__ __launch_bounds__(256) void convert_kernel(
    const float* __restrict__ X,  const float* __restrict__ Wq,
    const float* __restrict__ Wkv, const float* __restrict__ Wout,
    unsigned short* __restrict__ Xb, unsigned short* __restrict__ Wb,
    unsigned short* __restrict__ Wob) {
  int g = blockIdx.x * 256 + threadIdx.x;
  const float* src; unsigned short* dst; int gi;
  if (g < GX)                        { src = X;    dst = Xb;  gi = g; }
  else if ((g -= GX) < GWQ)          { src = Wq;   dst = Wb;  gi = g; }
  else if ((g -= GWQ) < GWKV)        { src = Wkv;  dst = Wb + (size_t)GWQ * 8; gi = g; }
  else                               { src = Wout; dst = Wob; gi = g - GWKV; }
  const float4* s4 = reinterpret_cast<const float4*>(src) + (size_t)gi * 2;
  float4 a = s4[0], b = s4[1];
  reinterpret_cast<uint4*>(dst)[gi] = pack8(a, b);
}

// ---------------------------------------------------------------------------
// MFMA GEMM 1 (m97-style, frozen): C = Xb[4096,1024] @ Wb[3072,1024]^T.
// NOTE (R12 lesson): natural dispatch d=y*24+x already pins bn-panel%8 ->
// XCD (24 % 8 == 0); explicit remap refuted (perturbs producer->consumer
// L2 placement). Q/K/V epilogues LDS-staged, coalesced 16B stores.
// ---------------------------------------------------------------------------
__global__ __launch_bounds__(256) void gemm_qkv_mfma(
    const unsigned short* __restrict__ Xb,
    const unsigned short* __restrict__ Wb,
    unsigned short* __restrict__ Qh,
    unsigned short* __restrict__ Kh,
    unsigned short* __restrict__ Vt) {
  // GEMM phase: As = smem[0:8192], Bs = smem[8192:16384]
  // Epilogues: reused as 128x136 staging buffer (17408 ushorts = 34 KB)
  __shared__ __align__(16) unsigned short smem[128 * 136];
  unsigned short* As = smem;
  unsigned short* Bs = smem + 128 * 64;
  const int tid  = threadIdx.x;
  const int lane = tid & 63, w = tid >> 6;
  const int wm = w >> 1, wn = w & 1;
  const int q = lane >> 4, c = lane & 15;
  const int bm0 = blockIdx.y * 128;
  const int bn0 = blockIdx.x * 128;
  const unsigned short* Ag = Xb + (size_t)bm0 * DD;
  const unsigned short* Bg = Wb + (size_t)bn0 * DD;

  floatx4 acc[4][4];
#pragma unroll
  for (int i = 0; i < 4; ++i)
#pragma unroll
    for (int j = 0; j < 4; ++j) acc[i][j] = (floatx4){0.f, 0.f, 0.f, 0.f};

  int prow[4], pch[4];
#pragma unroll
  for (int t = 0; t < 4; ++t) {
    int s = (w * 4 + t) * 64 + lane;
    prow[t] = s >> 3;
    pch[t]  = (s & 7) ^ (prow[t] & 7);
  }
  int aoff[4][2], boff[4][2];
#pragma unroll
  for (int i = 0; i < 4; ++i)
#pragma unroll
    for (int h = 0; h < 2; ++h) {
      aoff[i][h] = (wm * 64 + i * 16 + c) * 64 + (((q + h * 4) ^ (c & 7)) << 3);
      boff[i][h] = (wn * 64 + i * 16 + c) * 64 + (((q + h * 4) ^ (c & 7)) << 3);
    }

  for (int kk = 0; kk < DD; kk += 64) {
    __syncthreads();
#pragma unroll
    for (int t = 0; t < 4; ++t) {
      int i = w * 4 + t;
      ld16(&As[i * 512], &Ag[(size_t)prow[t] * DD + kk + pch[t] * 8]);
      ld16(&Bs[i * 512], &Bg[(size_t)prow[t] * DD + kk + pch[t] * 8]);
    }
    __syncthreads();
    bf16x8 af[4][2], bfr[4][2];
#pragma unroll
    for (int i = 0; i < 4; ++i)
#pragma unroll
      for (int h = 0; h < 2; ++h) {
        af[i][h]  = *reinterpret_cast<const bf16x8*>(&As[aoff[i][h]]);
        bfr[i][h] = *reinterpret_cast<const bf16x8*>(&Bs[boff[i][h]]);
      }
#pragma unroll
    for (int i = 0; i < 4; ++i)
#pragma unroll
      for (int j = 0; j < 4; ++j) {
        acc[i][j] = __builtin_amdgcn_mfma_f32_16x16x32_bf16(af[i][0], bfr[j][0], acc[i][j], 0, 0, 0);
        acc[i][j] = __builtin_amdgcn_mfma_f32_16x16x32_bf16(af[i][1], bfr[j][1], acc[i][j], 0, 0, 0);
      }
  }

  const int region = bn0 >> 10;   // 0=Q, 1=K, 2=V
  if (region < 2) {
    // ---- Q/K: stage [m][n] in LDS, then coalesced 16B stores along e ----
    // Q scale: e^-0.5 * log2(e) so attention can use raw exp2
    const float scl = (region == 0) ? 0.18033688011112042f : 1.0f;
    __syncthreads();   // all waves done with As/Bs reads before reuse
    unsigned short* tb = smem;   // [128 m][136 stride], col = n
#pragma unroll
    for (int i = 0; i < 4; ++i) {
#pragma unroll
      for (int j = 0; j < 4; ++j) {
        int n  = wn * 64 + j * 16 + c;
        int m0 = wm * 64 + i * 16 + q * 4;
#pragma unroll
        for (int reg = 0; reg < 4; ++reg)
          tb[(m0 + reg) * 136 + n] = f2bf(acc[i][j][reg] * scl);
      }
    }
    __syncthreads();
    unsigned short* dst = (region == 0) ? Qh : Kh;
    const int b   = bm0 >> 11;
    const int t0  = bm0 & 2047;
    const int nb0 = bn0 & 1023;
    const int oct = tid & 15;
    const int nb  = nb0 + oct * 8;
    const int h   = nb >> 6, e = nb & 63;
#pragma unroll
    for (int it = 0; it < 8; ++it) {
      int tr = it * 16 + (tid >> 4);
      uint4 vv = *reinterpret_cast<const uint4*>(&tb[tr * 136 + oct * 8]);
      *reinterpret_cast<uint4*>(
          &dst[((size_t)((b * HH + h) * TT + t0 + tr)) * EE + e]) = vv;
    }
  } else {
    // ---- V: transpose through LDS, then coalesced 16 B stores along t ----
    __syncthreads();   // all waves done with As/Bs reads before reuse
    unsigned short* tb = smem;   // [128 n][136 stride], col = m (t)
#pragma unroll
    for (int i = 0; i < 4; ++i) {
#pragma unroll
      for (int j = 0; j < 4; ++j) {
        int nl = wn * 64 + j * 16 + c;
        int ml = wm * 64 + i * 16 + q * 4;
        ushort4 pk;
        pk.x = f2bf(acc[i][j][0]);
        pk.y = f2bf(acc[i][j][1]);
        pk.z = f2bf(acc[i][j][2]);
        pk.w = f2bf(acc[i][j][3]);
        *reinterpret_cast<ushort4*>(&tb[nl * 136 + ml]) = pk;  // 8 B aligned
      }
    }
    __syncthreads();
    const int b  = bm0 >> 11;
    const int t0 = bm0 & 2047;
    const int nb0 = bn0 & 1023;
    const int lr = tid & 15;
#pragma unroll
    for (int it = 0; it < 8; ++it) {
      int nl = it * 16 + (tid >> 4);
      int nb = nb0 + nl;
      int h = nb >> 6, e = nb & 63;
      uint4 vv = *reinterpret_cast<const uint4*>(&tb[nl * 136 + lr * 8]);
      *reinterpret_cast<uint4*>(
          &Vt[((size_t)(b * HH + h) * EE + e) * TT + t0 + lr * 8]) = vv;
    }
  }
}

// ---------------------------------------------------------------------------
// MFMA flash attention v12 (best-known, frozen): no setprio (R15: removing
// it was -13% — m190 case: barrier-synced 2-wave blocks, prioritized MFMA
// starves partner wave's staging). Padded conflict-free V (reg-staged, T14
// async split), K gload_lds + XOR, MFMA row-sum softmax, exp2 softmax.
// 32x32 layouts: A/B: m|n=lane&31, k=(lane>>5)*8+j;
//                C/D: col=lane&31, row=(reg&3)+8*(reg>>2)+4*(lane>>5).
// XCD pinning: xcd=flat&7 (4 bh x 512 KB = 2 MB < 4 MB L2 per XCD).
// ---------------------------------------------------------------------------
#define NKT 32   // 2048 / 64 k-tiles
#define VST 68   // padded V row stride (ushorts): 136B = 2-bank shift/row

#define ATILE(P, PREF, VMC)                                                    \
  do {                                                                         \
    if (PREF) {                                                                \
      _Pragma("unroll")                                                        \
      for (int t = 0; t < 4; ++t) {                                            \
        vreg[t] = *reinterpret_cast<const uint4*>(vpre[t]);                    \
        vpre[t] += 64;                                                         \
      }                                                                        \
      _Pragma("unroll")                                                        \
      for (int t = 0; t < 4; ++t) {                                            \
        ld16(&Kbuf[((P) ^ 1) * 4096 + (t * 2 + w) * 512], kpre[t]);            \
        kpre[t] += 4096;                                                       \
      }                                                                        \
    }                                                                          \
    asm volatile("s_waitcnt vmcnt(" VMC ")" ::: "memory");                     \
    asm volatile("s_barrier" ::: "memory");                                    \
    bf16x8 kf[2][4];                                                           \
    _Pragma("unroll")                                                          \
    for (int nt = 0; nt < 2; ++nt)                                             \
      _Pragma("unroll")                                                        \
      for (int kc = 0; kc < 4; ++kc)                                           \
        kf[nt][kc] = *reinterpret_cast<const bf16x8*>(                         \
            &Kbuf[(P) * 4096 + koff[nt][kc]]);                                 \
    floatx16 sacc[2];                                                          \
    _Pragma("unroll")                                                          \
    for (int nt = 0; nt < 2; ++nt) {                                           \
      sacc[nt] = __builtin_amdgcn_mfma_f32_32x32x16_bf16(kf[nt][0], qf[0], zf, 0, 0, 0); \
      _Pragma("unroll")                                                        \
      for (int kc = 1; kc < 4; ++kc)                                           \
        sacc[nt] = __builtin_amdgcn_mfma_f32_32x32x16_bf16(kf[nt][kc], qf[kc], sacc[nt], 0, 0, 0); \
    }                                                                          \
    unsigned int pp[2][8];                                                     \
    _Pragma("unroll")                                                          \
    for (int nt = 0; nt < 2; ++nt)                                             \
      _Pragma("unroll")                                                        \
      for (int r = 0; r < 8; ++r) {                                            \
        float e0 = __builtin_amdgcn_exp2f(sacc[nt][2 * r]);                    \
        float e1 = __builtin_amdgcn_exp2f(sacc[nt][2 * r + 1]);                \
        pp[nt][r] = pack2u(e0, e1);                                            \
      }                                                                        \
    _Pragma("unroll")                                                          \
    for (int nt = 0; nt < 2; ++nt)                                             \
      _Pragma("unroll")                                                        \
      for (int kcp = 0; kcp < 2; ++kcp) {                                      \
        union { unsigned int u[4]; bf16x8 v; } pf;                             \
        pf.u[0] = pp[nt][4 * kcp + 0]; pf.u[1] = pp[nt][4 * kcp + 1];          \
        pf.u[2] = pp[nt][4 * kcp + 2]; pf.u[3] = pp[nt][4 * kcp + 3];          \
        lacc = __builtin_amdgcn_mfma_f32_32x32x16_bf16(pf.v, onesf.v, lacc, 0, 0, 0); \
        _Pragma("unroll")                                                      \
        for (int eh = 0; eh < 2; ++eh) {                                       \
          const int cc = nt * 4 + 2 * kcp;                                     \
          uint2 v0 = *reinterpret_cast<const uint2*>(                          \
              &Vbuf[(P) * 4352 + voff[eh][cc]]);                               \
          uint2 v1 = *reinterpret_cast<const uint2*>(                          \
              &Vbuf[(P) * 4352 + voff[eh][cc + 1]]);                           \
          union { unsigned int u[4]; bf16x8 v; } vf;                           \
          vf.u[0] = v0.x; vf.u[1] = v0.y; vf.u[2] = v1.x; vf.u[3] = v1.y;      \
          o_acc[eh] = __builtin_amdgcn_mfma_f32_32x32x16_bf16(pf.v, vf.v, o_acc[eh], 0, 0, 0); \
        }                                                                      \
      }                                                                        \
    if (PREF) {                                                                \
      asm volatile("s_waitcnt vmcnt(4)" ::: "memory");                         \
      _Pragma("unroll")                                                        \
      for (int t = 0; t < 4; ++t) {                                            \
        unsigned short* vd = &Vbuf[((P) ^ 1) * 4352 + vwoff[t]];               \
        *reinterpret_cast<uint2*>(vd)     = make_uint2(vreg[t].x, vreg[t].y);  \
        *reinterpret_cast<uint2*>(vd + 4) = make_uint2(vreg[t].z, vreg[t].w);  \
      }                                                                        \
      asm volatile("s_waitcnt lgkmcnt(0)" ::: "memory");                       \
    }                                                                          \
    asm volatile("s_barrier" ::: "memory");                                    \
  } while (0)

__global__ __launch_bounds__(128) void attn_kernel(
    const unsigned short* __restrict__ Qh,
    const unsigned short* __restrict__ Kh,
    const unsigned short* __restrict__ Vtg,
    unsigned short* __restrict__ Aw) {
  // Kbuf: [2][4096] at smem[0]; Vbuf: [2][64][VST=68] at smem[8192]
  __shared__ __align__(16) unsigned short smem[16896];   // 33 KB

  const int tid  = threadIdx.x;   // 0..127
  const int lane = tid & 63;
  const int w    = tid >> 6;      // 0..1: q-row half
  const int n31  = lane & 31;
  const int g    = lane >> 5;

  // XCD-aware remap (bijective over flat 0..1023): xcd = flat&7
  const int flat = blockIdx.y * 32 + blockIdx.x;
  const int idx  = flat >> 3;                    // 0..127
  const int bh   = (flat & 7) * 4 + (idx >> 5);  // 0..31
  const int qt   = idx & 31;                     // 0..31
  const size_t base = (size_t)bh * TT * EE;
  const unsigned short* Qp = Qh + base + (size_t)(qt * 64 + w * 32) * EE;
  const unsigned short* Kp = Kh + base;
  const unsigned short* Vp = Vtg + base;

  unsigned short* Kbuf = smem;          // [2][4096]
  unsigned short* Vbuf = smem + 8192;   // [2][64*VST = 4352]

  // all-ones bf16 B-fragment for the row-sum MFMA (bf16 1.0 = 0x3F80)
  union { unsigned int u[4]; bf16x8 v; } onesf;
  onesf.u[0] = 0x3F803F80u; onesf.u[1] = 0x3F803F80u;
  onesf.u[2] = 0x3F803F80u; onesf.u[3] = 0x3F803F80u;

  // persistent zero C-operand for the first QK^T MFMA of each chain
  const floatx16 zf = (floatx16)(0.0f);

  // Q B-frags in registers: row n31 (of this wave's 32), e-chunk kc*16+g*8
  bf16x8 qf[4];
#pragma unroll
  for (int kc = 0; kc < 4; ++kc)
    qf[kc] = *reinterpret_cast<const bf16x8*>(
        &Qp[(size_t)n31 * EE + kc * 16 + g * 8]);

  // staging slots: block = 128 threads; 8 KB tile = 512 slots -> 4/thread
  int srow[4], sch[4], voct[4], vwoff[4];
#pragma unroll
  for (int t = 0; t < 4; ++t) {
    int s = (t * 2 + w) * 64 + lane;
    srow[t] = s >> 3;
    sch[t]  = (s & 7) ^ (srow[t] & 7);   // K XOR swizzle (unchanged)
    voct[t] = s & 7;                     // V: linear octet, no swizzle
    vwoff[t] = srow[t] * VST + voct[t] * 8;
  }

  // ---- loop-invariant LDS read offsets (ushort units within one buffer) ----
  int koff[2][4];
#pragma unroll
  for (int nt = 0; nt < 2; ++nt) {
    const int krow = nt * 32 + n31;
#pragma unroll
    for (int kc = 0; kc < 4; ++kc)
      koff[nt][kc] = krow * 64 + (((kc * 2 + g) ^ (krow & 7)) << 3);
  }
  int voff[2][8];
#pragma unroll
  for (int eh = 0; eh < 2; ++eh) {
    const int vrow = eh * 32 + n31;
#pragma unroll
    for (int cc = 0; cc < 8; ++cc)
      voff[eh][cc] = vrow * VST + cc * 8 + g * 4;   // 2-bank/row shift: free
  }

  // ---- strength-reduced prefetch pointers (start at tile 1) ----
  const unsigned short* kpre[4];
  const unsigned short* vpre[4];
#pragma unroll
  for (int t = 0; t < 4; ++t) {
    kpre[t] = Kp + (size_t)(64 + srow[t]) * EE + sch[t] * 8;
    vpre[t] = Vp + (size_t)srow[t] * TT + 64 + voct[t] * 8;
  }

  floatx16 o_acc[2];              // [eh]
  o_acc[0] = (floatx16)(0.0f);
  o_acc[1] = (floatx16)(0.0f);
  floatx16 lacc = (floatx16)(0.0f);   // row-sums of P (all 32 cols equal)

  uint4 vreg[4];                  // in-flight V tile (reg-staged)

  // ---- prologue: tile 0. V(0) loads first (oldest), K(0) DMAs second ----
#pragma unroll
  for (int t = 0; t < 4; ++t)
    vreg[t] = *reinterpret_cast<const uint4*>(
        Vp + (size_t)srow[t] * TT + voct[t] * 8);
#pragma unroll
  for (int t = 0; t < 4; ++t)
    ld16(&Kbuf[(t * 2 + w) * 512], Kp + (size_t)srow[t] * EE + sch[t] * 8);
  asm volatile("s_waitcnt vmcnt(4)" ::: "memory");   // retire V(0) regs
#pragma unroll
  for (int t = 0; t < 4; ++t) {
    unsigned short* vd = &Vbuf[vwoff[t]];
    *reinterpret_cast<uint2*>(vd)     = make_uint2(vreg[t].x, vreg[t].y);
    *reinterpret_cast<uint2*>(vd + 4) = make_uint2(vreg[t].z, vreg[t].w);
  }
  asm volatile("s_waitcnt lgkmcnt(0)" ::: "memory");
  // K(0) x4 still in flight; tile 0's vmcnt(8) retires them.

  // tiles 0..29 (buffer parity literal per half), then peel 30 and 31
  for (int kt2 = 0; kt2 < 15; ++kt2) {
    ATILE(0, true, "8");
    ATILE(1, true, "8");
  }
  ATILE(0, true, "8");    // tile 30: prefetch 31 (K->Kbuf[1], V->Vbuf[1])
  ATILE(1, false, "0");   // tile 31: drain K(31), no prefetch

  // ---- epilogue: lacc[reg] already holds this lane's row total ----
  const int b = bh >> 4, h = bh & 15;
#pragma unroll
  for (int eh = 0; eh < 2; ++eh)
#pragma unroll
    for (int reg = 0; reg < 16; ++reg) {
      int qrl = (reg & 3) + 8 * (reg >> 2) + 4 * g;
      int t = qt * 64 + w * 32 + qrl;
      Aw[((size_t)(b * TT + t)) * DD + h * EE + eh * 32 + n31] =
          f2bf(o_acc[eh][reg] * (1.0f / lacc[reg]));
    }
}

// ---------------------------------------------------------------------------
// MFMA GEMM 2 (R8-proven, frozen — R16 dbuf variant reverted: counted-vmcnt
// dbuf was +3 us even at 2 blocks/CU, extending the m99-null):
// out = Aw @ Wob^T + bias. Tile 128x64x64, grid 512 = 2 blocks/CU.
// ---------------------------------------------------------------------------
__global__ __launch_bounds__(256) void gemm_out_mfma(
    const unsigned short* __restrict__ A,
    const unsigned short* __restrict__ Wob,
    const float* __restrict__ bias,
    float* __restrict__ out) {
  __shared__ __align__(16) unsigned short As[128 * 64];
  __shared__ __align__(16) unsigned short Bs[64 * 64];
  const int tid  = threadIdx.x;
  const int lane = tid & 63, w = tid >> 6;
  const int wm = w >> 1, wn = w & 1;
  const int q = lane >> 4, c = lane & 15;
  const int bm0 = blockIdx.y * 128;
  const int bn0 = blockIdx.x * 64;
  const unsigned short* Ag = A + (size_t)bm0 * DD;
  const unsigned short* Bg = Wob + (size_t)bn0 * DD;

  floatx4 acc[4][2];
#pragma unroll
  for (int i = 0; i < 4; ++i)
#pragma unroll
    for (int j = 0; j < 2; ++j) acc[i][j] = (floatx4){0.f, 0.f, 0.f, 0.f};

  int parow[4], pach[4];
#pragma unroll
  for (int t = 0; t < 4; ++t) {
    int s = (w * 4 + t) * 64 + lane;
    parow[t] = s >> 3;
    pach[t]  = (s & 7) ^ (parow[t] & 7);
  }
  int pbrow[2], pbch[2];
#pragma unroll
  for (int t = 0; t < 2; ++t) {
    int s = (w * 2 + t) * 64 + lane;
    pbrow[t] = s >> 3;
    pbch[t]  = (s & 7) ^ (pbrow[t] & 7);
  }

  for (int kk = 0; kk < DD; kk += 64) {
    __syncthreads();
#pragma unroll
    for (int t = 0; t < 4; ++t)
      ld16(&As[(w * 4 + t) * 512], &Ag[(size_t)parow[t] * DD + kk + pach[t] * 8]);
#pragma unroll
    for (int t = 0; t < 2; ++t)
      ld16(&Bs[(w * 2 + t) * 512], &Bg[(size_t)pbrow[t] * DD + kk + pbch[t] * 8]);
    __syncthreads();
    bf16x8 af[4][2], bfr[2][2];
#pragma unroll
    for (int h = 0; h < 2; ++h) {
      int ksw = ((q + h * 4) ^ (c & 7)) << 3;
#pragma unroll
      for (int i = 0; i < 4; ++i)
        af[i][h] = *reinterpret_cast<const bf16x8*>(&As[(wm * 64 + i * 16 + c) * 64 + ksw]);
#pragma unroll
      for (int j = 0; j < 2; ++j)
        bfr[j][h] = *reinterpret_cast<const bf16x8*>(&Bs[(wn * 32 + j * 16 + c) * 64 + ksw]);
    }
#pragma unroll
    for (int i = 0; i < 4; ++i)
#pragma unroll
      for (int j = 0; j < 2; ++j) {
        acc[i][j] = __builtin_amdgcn_mfma_f32_16x16x32_bf16(af[i][0], bfr[j][0], acc[i][j], 0, 0, 0);
        acc[i][j] = __builtin_amdgcn_mfma_f32_16x16x32_bf16(af[i][1], bfr[j][1], acc[i][j], 0, 0, 0);
      }
  }

#pragma unroll
  for (int i = 0; i < 4; ++i) {
#pragma unroll
    for (int j = 0; j < 2; ++j) {
      int n = bn0 + wn * 32 + j * 16 + c;
      float bv = bias[n];
#pragma unroll
      for (int reg = 0; reg < 4; ++reg) {
        int m = bm0 + wm * 64 + i * 16 + q * 4 + reg;
        out[(size_t)m * DD + n] = acc[i][j][reg] + bv;
      }
    }
  }
}

// ---------------------------------------------------------------------------
extern "C" void kernel_launch(void* const* d_in, const int* in_sizes, int n_in,
                              void* d_out, int out_size, void* d_ws, size_t ws_size,
                              hipStream_t stream) {
  const float* X    = (const float*)d_in[0];
  const float* Wq   = (const float*)d_in[1];
  const float* Wkv  = (const float*)d_in[2];
  const float* Wout = (const float*)d_in[3];
  const float* bout = (const float*)d_in[4];
  float* out = (float*)d_out;

  unsigned short* Qh  = (unsigned short*)d_ws;            // [32][2048][64]
  unsigned short* Kh  = Qh + (size_t)BT * DD;             // [32][2048][64]
  unsigned short* Vt  = Kh + (size_t)BT * DD;             // [32][64][2048]
  unsigned short* Aw  = Vt + (size_t)BT * DD;             // [4096][1024]
  unsigned short* Xb  = Aw;                               // OVERLAY: dead before attn writes Aw
  unsigned short* Wb  = Aw + (size_t)BT * DD;             // [3072][1024]
  unsigned short* Wob = Wb + (size_t)3 * 1024 * DD;       // [1024][1024]

  convert_kernel<<<dim3(4096), 256, 0, stream>>>(X, Wq, Wkv, Wout, Xb, Wb, Wob);
  gemm_qkv_mfma<<<dim3(24, 32), 256, 0, stream>>>(Xb, Wb, Qh, Kh, Vt);
  attn_kernel<<<dim3(32, 32), 128, 0, stream>>>(Qh, Kh, Vt, Aw);
  gemm_out_mfma<<<dim3(16, 32), 256, 0, stream>>>(Aw, Wob, bout, out);
}